// Round 6
// baseline (523.826 us; speedup 1.0000x reference)
//
#include <hip/hip_runtime.h>
#include <stdint.h>

// Problem dims (fixed by reference)
#define TOKENS 8192
#define DIN    4096
#define DOUT   4096

typedef short bf16x8 __attribute__((ext_vector_type(8)));  // 8 bf16 = 4 VGPRs
typedef float f32x4  __attribute__((ext_vector_type(4)));  // MFMA 16x16 accum

// ---- fp32 -> bf16 round-to-nearest-even (inputs finite) ----
__device__ __forceinline__ unsigned short f2bf(float f) {
    union { float f; unsigned int u; } v; v.f = f;
    return (unsigned short)((v.u + 0x7fffu + ((v.u >> 16) & 1u)) >> 16);
}

// ---- ternary int {-1,0,1} -> bf16 bit pattern (2 selects, no float math) ----
__device__ __forceinline__ unsigned short tern2bf(int v) {
    return v == 0 ? (unsigned short)0u
                  : (v > 0 ? (unsigned short)0x3F80u : (unsigned short)0xBF80u);
}

// ---- async global->LDS, 16B/lane; LDS dest = wave-uniform base + lane*16 ----
__device__ __forceinline__ void gload_lds16(const unsigned short* g, unsigned short* l) {
    __builtin_amdgcn_global_load_lds(
        (const __attribute__((address_space(1))) unsigned int*)g,
        (__attribute__((address_space(3))) unsigned int*)l,
        16, 0, 0);
}

// ================= fused prologue: one kernel, two jobs =================
#define WBLKS 1024
#define XBLKS 2048

__global__ __launch_bounds__(256) void fused_cvt(
    const float* __restrict__ x, const int* __restrict__ W,
    unsigned short* __restrict__ xb, unsigned short* __restrict__ Wt) {
    __shared__ unsigned short lds[64][264];   // [n_local][k_local], pitch 264
    const int t = threadIdx.x;

    if (blockIdx.x < WBLKS) {
        // ---- W transpose part: tile k0..k0+255, n0..n0+63 ----
        const int b  = blockIdx.x;
        const int k0 = (b >> 6) * 256;        // 16 k-tiles
        const int n0 = (b & 63) * 64;         // 64 n-tiles
        const int nl = 4 * (t & 15);          // n_local base this thread fills
#pragma unroll
        for (int it = 0; it < 16; ++it) {
            const int r = (t >> 4) + 16 * it; // k_local
            int4 v = *(const int4*)&W[(size_t)(k0 + r) * DOUT + n0 + nl];
            lds[nl + 0][r] = tern2bf(v.x);
            lds[nl + 1][r] = tern2bf(v.y);
            lds[nl + 2][r] = tern2bf(v.z);
            lds[nl + 3][r] = tern2bf(v.w);
        }
        __syncthreads();
        const int n = t >> 2;                 // 0..63
        const int s = t & 3;
        unsigned short* drow = Wt + (size_t)(n0 + n) * DIN + k0;
#pragma unroll
        for (int u = 0; u < 8; ++u) {
            const int k = u * 32 + s * 8;     // lanes 0-3 cover 64B contiguous
            *(uint4*)&drow[k] = *(const uint4*)&lds[n][k];
        }
    } else {
        // ---- x convert part: 8 chunks of 8 floats per thread ----
        const int b2 = blockIdx.x - WBLKS;    // 0..2047
        const int stride = XBLKS * 256;       // chunks per sweep
        int c = b2 * 256 + t;
        const float4* x4 = (const float4*)x;
        uint4* o = (uint4*)xb;                // 8 bf16 = 16B per chunk
#pragma unroll
        for (int j = 0; j < 8; ++j, c += stride) {
            float4 a = x4[2 * c];
            float4 bvec = x4[2 * c + 1];
            uint4 p;
            p.x = (unsigned)f2bf(a.x)    | ((unsigned)f2bf(a.y) << 16);
            p.y = (unsigned)f2bf(a.z)    | ((unsigned)f2bf(a.w) << 16);
            p.z = (unsigned)f2bf(bvec.x) | ((unsigned)f2bf(bvec.y) << 16);
            p.w = (unsigned)f2bf(bvec.z) | ((unsigned)f2bf(bvec.w) << 16);
            o[c] = p;
        }
    }
}

// ============ main GEMM: 128x256 tile, BK=32, 2 blocks/CU (TLP round) ============
// R6 theory: 4 sync structures all pinned at 44% MfmaUtil with 1 block/CU --
// the ~400 cyc/phase bubble is un-fillable without independent waves. This
// config doubles occupancy: acc shrinks to 64 regs (wave tile 64x64), LDS to
// 64 KB -> 2 blocks/CU, 4 waves/SIMD, VGPR budget 128.
//
// 8 waves (2M x 4N), wave tile 64x64 = 4 Mf x 4 Nf of 16x16x32, acc=16 f32x4.
// LDS: sA = 4-deep ring of 128x32 (8 KB each), sB = 2-deep of 256x32 (16 KB).
// Swizzle: LDS slot (row, q) holds global k-quad q ^ (row&3); staging
// pre-swizzles the global source (linear gload dest), reads apply same XOR.
// (4 quads only -> residual 4-way read conflict, cost 1.58x on reads; accepted.)
//
// Per tile t (2 phases, 8 MFMA each):
//   P0: read B(t) 4 + A(t) Mf0/1 2; stage A(t+2)->sA[(t+2)&3] (1 gload);
//       BAR; lgkm0; 8 MFMA; BAR
//   P1: read A(t) Mf2/3 2; stage B(t+2)->sB[t&1] (2 gloads); VM3;
//       BAR; lgkm0; 8 MFMA; BAR
// Ledger (induction-verified): after each P1's VM3, in-flight = exactly
// {A(t+2):1, B(t+2):2}; VM3 confirms A(t+1),B(t+1) needed next tile, whose
// reads follow the next barrier (race-free cross-wave). WAR: sB[t&1] re-staged
// at P1, after P0's lgkm-drained reads + barrier; sA ring slot idle 2 tiles.
// Prologue: A0,B0,A1,B1 (6 loads), VM3 (drains A0,B0; leaves A1,B1), BAR.
// Tail: tiles 124..127 peeled; VM0 at tile 126 P1.
#define BM 128
#define BN 256
#define BK 32

#define BAR  __builtin_amdgcn_s_barrier()
#define SB0  __builtin_amdgcn_sched_barrier(0)
#define SP1  __builtin_amdgcn_s_setprio(1)
#define SP0  __builtin_amdgcn_s_setprio(0)
#define VM3  asm volatile("s_waitcnt vmcnt(3)" ::: "memory")
#define VM0  asm volatile("s_waitcnt vmcnt(0)" ::: "memory")
#define LGK0 asm volatile("s_waitcnt lgkmcnt(0)" ::: "memory")

#define STG_A(DBUF, kt) gload_lds16(gA + (kt), &sA[DBUF][wave * 512])
#define STG_B(DBUF, kt)                                                     \
    do {                                                                    \
        gload_lds16(gB + (kt), &sB[DBUF][wave * 512]);                      \
        gload_lds16(gB + (size_t)128 * DIN + (kt),                          \
                    &sB[DBUF][4096 + wave * 512]);                          \
    } while (0)

// One K-tile: ABUF in sA ring, BBUF in sB pair; STGA at P0, STGB+VMX at P1.
#define TILE(ABUF, BBUF, STGA, STGB, VMX)                                   \
    {                                                                       \
        bf16x8 bq[4], a0, a1;                                               \
        _Pragma("unroll") for (int ni = 0; ni < 4; ++ni)                    \
            bq[ni] = *(const bf16x8*)&sB[BBUF][rowB + ni * 512];            \
        a0 = *(const bf16x8*)&sA[ABUF][rowA];                               \
        a1 = *(const bf16x8*)&sA[ABUF][rowA + 512];                         \
        STGA;                                                               \
        BAR; LGK0; SB0; SP1;                                                \
        _Pragma("unroll") for (int ni = 0; ni < 4; ++ni) {                  \
            acc[0][ni] = __builtin_amdgcn_mfma_f32_16x16x32_bf16(           \
                a0, bq[ni], acc[0][ni], 0, 0, 0);                           \
            acc[1][ni] = __builtin_amdgcn_mfma_f32_16x16x32_bf16(           \
                a1, bq[ni], acc[1][ni], 0, 0, 0);                           \
        }                                                                   \
        SP0; BAR;                                                           \
        a0 = *(const bf16x8*)&sA[ABUF][rowA + 1024];                        \
        a1 = *(const bf16x8*)&sA[ABUF][rowA + 1536];                        \
        STGB;                                                               \
        VMX;                                                                \
        BAR; LGK0; SB0; SP1;                                                \
        _Pragma("unroll") for (int ni = 0; ni < 4; ++ni) {                  \
            acc[2][ni] = __builtin_amdgcn_mfma_f32_16x16x32_bf16(           \
                a0, bq[ni], acc[2][ni], 0, 0, 0);                           \
            acc[3][ni] = __builtin_amdgcn_mfma_f32_16x16x32_bf16(           \
                a1, bq[ni], acc[3][ni], 0, 0, 0);                           \
        }                                                                   \
        SP0; BAR;                                                           \
    }

__global__ __launch_bounds__(512, 4) void gemm_bt(
    const unsigned short* __restrict__ A,   // [M][K] bf16
    const unsigned short* __restrict__ B,   // [N][K] bf16 (W transposed)
    float* __restrict__ C) {                // [M][N] fp32
    const int K = DIN, N = DOUT;

    __shared__ __align__(16) unsigned short sA[4][BM * BK];  // 4 x 8 KB ring
    __shared__ __align__(16) unsigned short sB[2][BN * BK];  // 2 x 16 KB

    const int tid  = threadIdx.x;
    const int wave = tid >> 6;
    const int lane = tid & 63;
    const int wm = wave >> 2;               // 0..1  (M, 64-row halves)
    const int wn = wave & 3;                // 0..3  (N, 64-col quarters)

    // ---- T1: XCD-aware bijective block swizzle (1024 wgs, 8 XCDs, 128/XCD) ----
    const int wg  = blockIdx.x + gridDim.x * blockIdx.y;   // hardware linear id
    const int xcd = wg & 7;
    const int idx = wg >> 3;                               // 0..127 within XCD
    const int bx  = (xcd & 1) * 8 + (idx & 7);             // 0..15  (N tiles)
    const int by  = (xcd >> 1) * 16 + (idx >> 3);          // 0..63  (M tiles)

    // ---- staging addressing: wave w stages rows 16w..16w+15 of each 128-row half
    const int lrow = lane >> 2;             // 0..15 row within wave chunk
    const int qsrc = (lane & 3) ^ (lrow & 3);   // pre-swizzled global k-quad
    const unsigned short* gA =
        A + (size_t)(by * BM + wave * 16 + lrow) * K + qsrc * 8;
    const unsigned short* gB =
        B + (size_t)(bx * BN + wave * 16 + lrow) * K + qsrc * 8;

    // ---- fragment read addressing (swizzled ds_read) ----
    const int mrow = lane & 15;
    const int kgrp = lane >> 4;             // 0..3 k-quad
    const int qrd  = (kgrp ^ (mrow & 3)) * 8;   // swizzled quad offset (elems)
    const int rowA = (wm * 64 + mrow) * 32 + qrd;
    const int rowB = (wn * 64 + mrow) * 32 + qrd;

    f32x4 acc[4][4];
#pragma unroll
    for (int i = 0; i < 4; ++i)
#pragma unroll
        for (int j = 0; j < 4; ++j) {
            f32x4 z = {0.f, 0.f, 0.f, 0.f};
            acc[i][j] = z;
        }

    // ---- prologue: A0,B0,A1,B1; VM3 drains A0,B0 and leaves {A1,B1} ----
    STG_A(0, 0);
    STG_B(0, 0);
    STG_A(1, 32);
    STG_B(1, 32);
    VM3;
    BAR;

    // ---- main loop: 31 iters x 4 tiles (tiles 0..123), all bufs compile-time ----
    for (int kt = 0; kt < 3968; kt += 128) {
        TILE(0, 0, STG_A(2, kt + 64),  STG_B(0, kt + 64),  VM3)
        TILE(1, 1, STG_A(3, kt + 96),  STG_B(1, kt + 96),  VM3)
        TILE(2, 0, STG_A(0, kt + 128), STG_B(0, kt + 128), VM3)
        TILE(3, 1, STG_A(1, kt + 160), STG_B(1, kt + 160), VM3)
    }

    // ---- peeled tail: tiles 124..127 ----
    TILE(0, 0, STG_A(2, 4032), STG_B(0, 4032), VM3)   // 124 stages t126
    TILE(1, 1, STG_A(3, 4064), STG_B(1, 4064), VM3)   // 125 stages t127
    TILE(2, 0, , , VM0)                               // 126: drain for 127
    TILE(3, 1, , , )                                  // 127

    // ---- epilogue: C/D layout col=lane&15, row=(lane>>4)*4+reg; NT stores ----
    float* Cw = C + (size_t)(by * BM + wm * 64 + kgrp * 4) * N
                + (size_t)(bx * BN + wn * 64 + mrow);
#pragma unroll
    for (int mi = 0; mi < 4; ++mi)
#pragma unroll
        for (int ni = 0; ni < 4; ++ni)
#pragma unroll
            for (int r = 0; r < 4; ++r)
                __builtin_nontemporal_store(acc[mi][ni][r],
                                            &Cw[(size_t)(mi * 16 + r) * N + ni * 16]);
}

// ============ safety-net fallback if ws is too small (slow but correct) ============
__global__ void gemm_naive(const float* __restrict__ x, const int* __restrict__ W,
                           float* __restrict__ out) {
    int n = blockIdx.x * blockDim.x + threadIdx.x;
    int t = blockIdx.y;
    const float* xr = x + (size_t)t * DIN;
    float acc = 0.f;
    for (int k = 0; k < DIN; ++k)
        acc += xr[k] * (float)W[(size_t)k * DOUT + n];
    out[(size_t)t * DOUT + n] = acc;
}

extern "C" void kernel_launch(void* const* d_in, const int* in_sizes, int n_in,
                              void* d_out, int out_size, void* d_ws, size_t ws_size,
                              hipStream_t stream) {
    const float* x = (const float*)d_in[0];
    const int*   W = (const int*)d_in[1];
    float* out = (float*)d_out;

    const size_t xb_elems = (size_t)TOKENS * DIN;           // 64 MB bf16
    const size_t wt_elems = (size_t)DIN * DOUT;             // 32 MB bf16
    const size_t need = (xb_elems + wt_elems) * sizeof(unsigned short);

    if (ws_size < need) {   // should not happen; correctness safety net
        dim3 g(DOUT / 256, TOKENS);
        gemm_naive<<<g, 256, 0, stream>>>(x, W, out);
        return;
    }

    unsigned short* xb = (unsigned short*)d_ws;
    unsigned short* Wt = xb + xb_elems;

    fused_cvt<<<WBLKS + XBLKS, 256, 0, stream>>>(x, W, xb, Wt);

    dim3 grid(DOUT / BN, TOKENS / BM);   // (16, 64)
    gemm_bt<<<grid, 512, 0, stream>>>(xb, Wt, out);
}